// Round 5
// baseline (373.065 us; speedup 1.0000x reference)
//
#include <hip/hip_runtime.h>
#include <cstdint>
#include <cstddef>

#define NLV 5
#define NIMG 4
#define NSEL 4507          // 1000+1000+1000+1000+507 selected per image
#define TSEL (NIMG * NSEL)
#define POSTN 1000
#define TCAP 8192          // boundary-bin candidate cap
#define TTCAP 2048         // sub-boundary (tie-of-tie) cap
#define NHB 16             // sub-histograms per (image,level)
#define PBLK 64            // pick units per (image,level)
#define PCH 1875           // max chunk for pick (120000/64)

// MAGIC handshake values (workspace is poisoned with a constant fill pattern;
// these never collide with it). Flags are reset by the NEXT dispatch so a
// stale-MAGIC shortcut can never expose un-zeroed counters.
#define MG_SUB 0x5EEDF000u
#define MG_RDY 0x5EEDA000u
#define MG_KDN 0x5EEDC000u

__device__ const int d_W[NLV]    = {200, 100, 50, 25, 13};
__device__ const int d_NL[NLV]   = {120000, 30000, 7500, 1875, 507};
__device__ const int d_KOFF[6]   = {0, 120000, 150000, 157500, 159375, 159882};
__device__ const int d_LOFF[6]   = {0, 1000, 2000, 3000, 4000, 4507};
__device__ const int d_KL[NLV]   = {1000, 1000, 1000, 1000, 507};

struct Ptrs {
    const float* obj[NLV];
    const float* del[NLV];
    const float* anch;
};

// order-preserving map: dk ascending <=> float descending
__device__ inline unsigned int dkey_of(float f) {
    unsigned int u = __float_as_uint(f);
    unsigned int mk = (u & 0x80000000u) ? ~u : (u | 0x80000000u);
    return ~mk;
}
__device__ inline float logit_from_dkey(unsigned int dk) {
    unsigned int mk = ~dk;
    unsigned int u = (mk & 0x80000000u) ? (mk & 0x7fffffffu) : ~mk;
    return __uint_as_float(u);
}

__device__ inline unsigned int aload(const unsigned int* p, int order) {
    return __hip_atomic_load(p, order, __HIP_MEMORY_SCOPE_AGENT);
}
__device__ inline void astore(unsigned int* p, unsigned int v, int order) {
    __hip_atomic_store(p, v, order, __HIP_MEMORY_SCOPE_AGENT);
}

// ============================================================================
// Stage 1: hist + thresh + pick fused. 1280 blocks x 256 thr, LDS ~30.1KB
// -> exactly 5 blocks/CU x 256 CU = 1280: ALL blocks co-resident, so
// intra-kernel spin-waits cannot deadlock. No grid.sync (round-4 lesson:
// ~30us each on 8-XCD MI355X). Cross-block data moves via agent-scope
// atomics (per-XCD L2s are not coherent for plain stores within a kernel).
// ============================================================================
__global__ __launch_bounds__(256) void k_htp(Ptrs P, unsigned int* hist,
        unsigned int* subflag, unsigned int* ready, unsigned int* thr,
        int* scnt, int* tcnt, int* cg, float* cl,
        unsigned long long* tiebuf, unsigned int* kdone) {
    int bid = blockIdx.x, tid = threadIdx.x;
    __shared__ union {
        unsigned int h[2048];                               //  8KB hist
        struct { int sp[PCH]; float sl[PCH];
                 unsigned long long tb[PCH]; } pk;          // 30KB pick
    } U;
    __shared__ unsigned int pw4[4];
    __shared__ unsigned int s_b0;
    __shared__ int nselS, ntieS, sbaseS, tbaseS;

    // reset kdone for this iteration (used by stage-4 dispatch, strictly later)
    if (bid < NIMG * NLV && tid == 0) kdone[bid] = 0;

    // ---- phase H: sub-histograms (blocks 0..319; proven 256-thr config) ----
    if (bid < NIMG * NLV * NHB) {
        int hnl = bid >> 4, sub = bid & 15;
        int l = hnl % NLV, n = hnl / NLV;
        if (d_KL[l] < d_NL[l]) {
            for (int i = tid; i < 2048; i += 256) U.h[i] = 0;
            __syncthreads();
            int nl_sz = d_NL[l];
            const float* ob = P.obj[l] + (size_t)n * nl_sz;
            int chunk = (nl_sz + NHB - 1) / NHB;
            int beg = sub * chunk, end = min(beg + chunk, nl_sz);
            for (int t = beg + tid; t < end; t += 256)
                atomicAdd(&U.h[dkey_of(ob[t]) >> 21], 1u);   // LDS atomic
            __syncthreads();
            unsigned int* op = hist + ((size_t)hnl * NHB + sub) * 2048;
            for (int i = tid; i < 2048; i += 256)
                astore(&op[i], U.h[i], __ATOMIC_RELAXED);    // device-coherent
            __syncthreads();   // vmcnt drained before barrier -> stores complete
            if (tid == 0 && sub != 0)
                astore(&subflag[bid], MG_SUB + (unsigned)bid, __ATOMIC_RELEASE);
        }
    }

    // ---- phase T: threshold (one block per (n,l): sub==0) ----
    if (bid < NIMG * NLV * NHB && (bid & 15) == 0) {
        int hnl = bid >> 4, l = hnl % NLV;
        if (d_KL[l] < d_NL[l]) {
            if (tid < 15) {                                  // wait 15 peers
                unsigned int want = MG_SUB + (unsigned)(bid + 1 + tid);
                while (aload(&subflag[bid + 1 + tid], __ATOMIC_ACQUIRE) != want)
                    __builtin_amdgcn_s_sleep(8);
            }
            __syncthreads();
            // reduce 16 sub-hists; thread t owns bins [8t, 8t+8)
            unsigned int bins[8];
            #pragma unroll
            for (int i = 0; i < 8; ++i) bins[i] = 0;
            const unsigned int* hb = hist + (size_t)hnl * NHB * 2048;
            for (int sh = 0; sh < NHB; ++sh) {
                #pragma unroll
                for (int i = 0; i < 8; ++i)
                    bins[i] += aload(&hb[sh * 2048 + tid * 8 + i], __ATOMIC_RELAXED);
            }
            unsigned int s = 0;
            #pragma unroll
            for (int i = 0; i < 8; ++i) s += bins[i];
            int w4 = tid >> 6, lane = tid & 63;
            unsigned int ps = s;
            #pragma unroll
            for (int d = 1; d < 64; d <<= 1) {
                unsigned int t2 = (unsigned int)__shfl_up((int)ps, d, 64);
                if (lane >= d) ps += t2;
            }
            if (lane == 63) pw4[w4] = ps;
            __syncthreads();
            unsigned int base = 0;
            #pragma unroll
            for (int ww = 0; ww < 4; ++ww) if (ww < w4) base += pw4[ww];
            unsigned int exc = base + ps - s;                // exclusive before bin 8t
            unsigned int target = (unsigned int)d_KL[l];
            unsigned int cum = exc;
            #pragma unroll
            for (int i = 0; i < 8; ++i) {
                if (cum < target && target <= cum + bins[i]) {   // exactly one hit
                    astore(&thr[hnl * 2],     (unsigned int)(tid * 8 + i), __ATOMIC_RELAXED);
                    astore(&thr[hnl * 2 + 1], cum, __ATOMIC_RELAXED);
                }
                cum += bins[i];
            }
            if (tid == 0) {
                astore((unsigned int*)&scnt[hnl], 0u, __ATOMIC_RELAXED);
                astore((unsigned int*)&tcnt[hnl], 0u, __ATOMIC_RELAXED);
            }
            __syncthreads();   // drain thr/scnt/tcnt stores
            if (tid == 0)
                astore(&ready[hnl], MG_RDY + (unsigned)hnl, __ATOMIC_RELEASE);
        }
    }

    // ---- phase P: pick winners (all 1280 blocks, original k_pick mapping) --
    {
        int nlid = bid >> 6, pb = bid & 63;
        int n = nlid / NLV, l = nlid % NLV;
        int nl_sz = d_NL[l], kl = d_KL[l];
        const float* ob = P.obj[l] + (size_t)n * nl_sz;
        int cbase = n * NSEL + d_LOFF[l];
        int koff = d_KOFF[l];
        int Wl = d_W[l], HW = Wl * Wl;
        int chunk = (nl_sz + PBLK - 1) / PBLK;
        int beg = pb * chunk, end = min(beg + chunk, nl_sz);

        if (kl >= nl_sz) {                       // level 4: deterministic slots
            for (int t = beg + tid; t < end; t += 256) {
                int a = t / HW, rem = t - a * HW;
                int p = rem * 3 + a;
                cg[cbase + p] = koff + p;
                cl[cbase + p] = ob[t];
            }
            return;
        }
        if (tid == 0) {
            unsigned int want = MG_RDY + (unsigned)nlid;
            while (aload(&ready[nlid], __ATOMIC_ACQUIRE) != want)
                __builtin_amdgcn_s_sleep(8);
            s_b0 = aload(&thr[nlid * 2], __ATOMIC_RELAXED);
            nselS = 0; ntieS = 0;
        }
        __syncthreads();                         // also fences hist-phase LDS reads
        unsigned int b0 = s_b0;
        for (int t = beg + tid; t < end; t += 256) {
            float lg = ob[t];
            unsigned int dk = dkey_of(lg);
            unsigned int bin = dk >> 21;
            if (bin < b0) {
                int pos = atomicAdd(&nselS, 1);  // LDS atomic
                int a = t / HW, rem = t - a * HW;
                U.pk.sp[pos] = rem * 3 + a;
                U.pk.sl[pos] = lg;
            } else if (bin == b0) {
                int pos = atomicAdd(&ntieS, 1);
                int a = t / HW, rem = t - a * HW;
                U.pk.tb[pos] = ((unsigned long long)dk << 17) |
                               (unsigned long long)(unsigned int)(rem * 3 + a);
            }
        }
        __syncthreads();
        if (tid == 0) {
            sbaseS = atomicAdd(&scnt[nlid], nselS);  // device-scope RMW
            tbaseS = atomicAdd(&tcnt[nlid], ntieS);
        }
        __syncthreads();
        int ns = nselS, nt = ntieS, sb = sbaseS, tbs = tbaseS;
        for (int i = tid; i < ns; i += 256) {
            cg[cbase + sb + i] = koff + U.pk.sp[i];
            cl[cbase + sb + i] = U.pk.sl[i];
        }
        for (int i = tid; i < nt; i += 256) {
            int slot = tbs + i;
            if (slot < TCAP) tiebuf[(size_t)nlid * TCAP + slot] = U.pk.tb[i];
        }
    }
}

// ============================================================================
// Stage 2: tie + build + sort (20 blocks) — round-3 proven. Also resets the
// stage-1 flags for the next iteration (strictly after their use).
// ============================================================================
__global__ __launch_bounds__(1024) void k_tbs(Ptrs P, const unsigned int* thr,
                                              const int* tcnt,
                                              const unsigned long long* tiebuf,
                                              int* cg, float* cl,
                                              unsigned long long* skey,
                                              float4* sboxL, float* slogL,
                                              int* ccnt,
                                              unsigned int* subflag, unsigned int* ready) {
#pragma clang fp contract(off)
    __shared__ union {
        struct { unsigned long long kk[TCAP];
                 unsigned long long tt[TTCAP];
                 unsigned int h2[2048]; } tie;               // 88KB (max)
        struct { unsigned long long s[1024];
                 float4 bx[1024];
                 float lg[1024]; } srt;                      // 28KB
    } U;
    __shared__ unsigned int wpre[16];
    __shared__ unsigned int s_b1, s_before;
    __shared__ int ctr, ttc;

    int l = blockIdx.x, n = blockIdx.y;
    int nl = n * NLV + l;
    int tid = threadIdx.x, w = tid >> 6, lane = tid & 63;
    int kl = d_KL[l], nl_sz = d_NL[l];
    int cbase = n * NSEL + d_LOFF[l];
    int koff = d_KOFF[l];

    if (tid == 0) ready[nl] = 0;                 // reset stage-1 flags
    if (tid < 16) subflag[nl * 16 + tid] = 0;

    // ---- phase A: boundary-bin candidates, radix-refined ----
    if (kl < nl_sz) {
        int c = min(tcnt[nl], TCAP);
        unsigned int cnt_lt = thr[nl * 2 + 1];
        int need = kl - (int)cnt_lt;
        if (tid == 0) { ctr = 0; ttc = 0; }
        U.tie.h2[tid] = 0; U.tie.h2[tid + 1024] = 0;
        for (int i = tid; i < c; i += 1024) U.tie.kk[i] = tiebuf[(size_t)nl * TCAP + i];
        __syncthreads();
        for (int i = tid; i < c; i += 1024)
            atomicAdd(&U.tie.h2[(unsigned int)((U.tie.kk[i] >> 27) & 0x7ffull)], 1u);
        __syncthreads();
        unsigned int v0 = U.tie.h2[2 * tid], v1 = U.tie.h2[2 * tid + 1];
        unsigned int s = v0 + v1, ps = s;
        #pragma unroll
        for (int d = 1; d < 64; d <<= 1) {
            unsigned int t2 = (unsigned int)__shfl_up((int)ps, d, 64);
            if (lane >= d) ps += t2;
        }
        if (lane == 63) wpre[w] = ps;
        __syncthreads();
        unsigned int base = 0;
        #pragma unroll
        for (int ww = 0; ww < 16; ++ww) if (ww < w) base += wpre[ww];
        unsigned int incl = base + ps;
        unsigned int target = (unsigned int)need;
        unsigned int exc0 = incl - s, inc0 = incl - v1;
        unsigned int exc1 = inc0,    inc1 = incl;
        if (exc0 < target && target <= inc0) { s_b1 = 2 * tid;     s_before = exc0; }
        if (exc1 < target && target <= inc1) { s_b1 = 2 * tid + 1; s_before = exc1; }
        __syncthreads();
        unsigned int b1 = s_b1;
        int before = (int)s_before;
        for (int i = tid; i < c; i += 1024) {
            unsigned long long ki = U.tie.kk[i];
            unsigned int sb = (unsigned int)((ki >> 27) & 0x7ffull);
            if (sb < b1) {                       // sure winner, arbitrary slot
                int slot = atomicAdd(&ctr, 1);
                int p = (int)(ki & 0x1ffffull);
                cg[cbase + (int)cnt_lt + slot] = koff + p;
                cl[cbase + (int)cnt_lt + slot] = logit_from_dkey((unsigned int)(ki >> 17));
            } else if (sb == b1) {
                int j = atomicAdd(&ttc, 1);
                if (j < TTCAP) U.tie.tt[j] = ki;
            }
        }
        __syncthreads();
        int c2 = min(ttc, TTCAP);
        int need2 = need - before;
        for (int i = tid; i < c2; i += 1024) {
            unsigned long long ki = U.tie.tt[i];
            int rank = 0;
            for (int j = 0; j < c2; ++j) rank += (U.tie.tt[j] < ki) ? 1 : 0;
            if (rank < need2) {                  // ranks unique (p unique)
                int p = (int)(ki & 0x1ffffull);
                cg[cbase + (int)cnt_lt + before + rank] = koff + p;
                cl[cbase + (int)cnt_lt + before + rank] = logit_from_dkey((unsigned int)(ki >> 17));
            }
        }
    }
    __syncthreads();   // phase A LDS dead; cg/cl visible block-wide

    // ---- phase B: decode, clip, validity ----
    {
        int j = tid;
        unsigned long long key;
        float4 box;
        float lgv;
        if (j >= kl) {                           // padding slot
            key = ((unsigned long long)0xFFFFFFFFu << 27) | (unsigned long long)j;
            box = make_float4(0.f, 0.f, 0.f, 0.f);
            lgv = 0.f;
        } else {
            int sidx = cbase + j;
            int gidx = cg[sidx];
            float lg = cl[sidx];
            int p = gidx - koff;
            int Wl = d_W[l];
            int HW = Wl * Wl;
            int a = p % 3, hw = p / 3;
            int hq = hw / Wl, wq = hw - hq * Wl;
            const float* dl = P.del[l];
            size_t dbase = (size_t)(n * 12 + a * 4) * HW + (size_t)hq * Wl + wq;
            float dx = dl[dbase], dy = dl[dbase + HW];
            float dw = dl[dbase + 2 * (size_t)HW], dh = dl[dbase + 3 * (size_t)HW];
            const float* an = P.anch + 4 * (size_t)gidx;
            float ax1 = an[0], ay1 = an[1], ax2 = an[2], ay2 = an[3];
            float wa = ax2 - ax1, ha = ay2 - ay1;
            float cxa = ax1 + 0.5f * wa, cya = ay1 + 0.5f * ha;
            const float CLIPC = (float)4.135166556742356;
            dw = fminf(dw, CLIPC); dh = fminf(dh, CLIPC);
            float cx = dx * wa + cxa;
            float cy = dy * ha + cya;
            float ww2 = expf(dw) * wa;
            float hh2 = expf(dh) * ha;
            float x1 = cx - 0.5f * ww2, y1 = cy - 0.5f * hh2;
            float x2 = cx + 0.5f * ww2, y2 = cy + 0.5f * hh2;
            x1 = fminf(fmaxf(x1, 0.0f), 800.0f);
            y1 = fminf(fmaxf(y1, 0.0f), 800.0f);
            x2 = fminf(fmaxf(x2, 0.0f), 800.0f);
            y2 = fminf(fmaxf(y2, 0.0f), 800.0f);
            bool valid = (x2 - x1 >= 1e-3f) && (y2 - y1 >= 1e-3f);
            box = make_float4(x1, y1, x2, y2);
            lgv = lg;
            unsigned int sk = valid ? dkey_of(lg) : 0xffffffffu;
            key = ((unsigned long long)sk << 27) |
                  ((unsigned long long)(unsigned int)p << 10) | (unsigned long long)j;
        }
        U.srt.s[j] = key;
        U.srt.bx[j] = box;
        U.srt.lg[j] = lgv;
    }
    __syncthreads();

    // ---- phase C: bitonic sort of 1024 keys (512 active) ----
    for (int k = 2; k <= 1024; k <<= 1) {
        for (int j2 = k >> 1; j2 > 0; j2 >>= 1) {
            if (tid < 512) {
                int i = ((tid & ~(j2 - 1)) << 1) | (tid & (j2 - 1));
                int ix = i | j2;
                bool up = ((i & k) == 0);
                unsigned long long A = U.srt.s[i], B = U.srt.s[ix];
                if ((A > B) == up) { U.srt.s[i] = B; U.srt.s[ix] = A; }
            }
            __syncthreads();
        }
    }
    {
        int e = tid;
        unsigned long long key = U.srt.s[e];
        int j = (int)(key & 0x3ffull);
        skey[(size_t)nl * 1024 + e] = key;
        sboxL[(size_t)nl * 1024 + e] = U.srt.bx[j];
        slogL[(size_t)nl * 1024 + e] = U.srt.lg[j];
        bool v = (key >> 27) != 0xFFFFFFFFull;
        bool vn = (e < 1023) ? ((U.srt.s[e + 1] >> 27) != 0xFFFFFFFFull) : false;
        if (e == 0 && !v) ccnt[nl] = 0;
        if (v && (e == 1023 || !vn)) ccnt[nl] = e + 1;
    }
}

// ============================================================================
// Stage 3: pairwise suppression mask, whole-chip parallel (round-1 lesson:
// never serialize this). blockIdx.x==0 blocks also zero this (n,l)'s output
// slice — strictly before the rank writes in the next dispatch.
// ============================================================================
__global__ __launch_bounds__(256) void k_mask(const float4* sboxL, const int* ccnt,
                                              unsigned long long* MT, float* out) {
#pragma clang fp contract(off)
    int n = blockIdx.z, l = blockIdx.y;
    int ci = blockIdx.x >> 4, cj = blockIdx.x & 15;
    int nl = n * NLV + l;
    int tid = threadIdx.x;
    if (blockIdx.x == 0) {                       // zero out-slice (seg=200)
        int seg = POSTN / NLV;
        for (int i = tid; i < seg; i += 256) {
            int idx = n * POSTN + l * seg + i;
            ((float4*)out)[idx] = make_float4(0.f, 0.f, 0.f, 0.f);
            out[NIMG * POSTN * 4 + idx] = 0.f;
        }
    }
    int cnt = ccnt[nl];
    int nw = (cnt + 63) / 64;
    if (cj < ci || cj >= nw) return;
    __shared__ float4 bi[64], bj[64];
    float off = (float)l * 801.0f;
    if (tid < 64) {
        float4 b = sboxL[nl * 1024 + cj * 64 + tid];
        bj[tid] = make_float4(b.x + off, b.y + off, b.z + off, b.w + off);
    } else if (tid < 128) {
        float4 b = sboxL[nl * 1024 + ci * 64 + (tid - 64)];
        bi[tid - 64] = make_float4(b.x + off, b.y + off, b.z + off, b.w + off);
    }
    __syncthreads();
    int w = tid >> 6, lane = tid & 63;
    float4 B = bj[lane];
    float a2 = (B.z - B.x) * (B.w - B.y);
    unsigned long long* outp = MT + ((size_t)nl * 16 + cj) * 1024 + ci * 64;
    #pragma unroll
    for (int t = 0; t < 16; ++t) {
        int i = w * 16 + t;
        float4 A = bi[i];
        float a1 = (A.z - A.x) * (A.w - A.y);
        float ltx = fmaxf(A.x, B.x), lty = fmaxf(A.y, B.y);
        float rbx = fminf(A.z, B.z), rby = fminf(A.w, B.w);
        float wx = fmaxf(rbx - ltx, 0.f), wy = fmaxf(rby - lty, 0.f);
        float inter = wx * wy;
        float iou = inter / ((a1 + a2) - inter);   // NaN (0/0) -> false, like jnp
        unsigned long long word = __ballot(iou > 0.7f);
        if (lane == 0) outp[i] = word;
    }
}

// ============================================================================
// Stage 4: scan + rank fused at 20 blocks (round-3 parallel shape). The
// cross-level dependency inside an image is handled with agent-scope keepL
// stores + MAGIC kdone flags; 20 blocks are trivially co-resident.
// ============================================================================
__global__ __launch_bounds__(1024) void k_scanrank2(const unsigned long long* MT,
                                                    const int* ccnt,
                                                    const unsigned long long* skey,
                                                    const float4* sboxL, const float* slogL,
                                                    unsigned long long* keepL,
                                                    unsigned int* kdone, float* out) {
    int l = blockIdx.x, n = blockIdx.y;
    int nl = n * NLV + l;
    int tid = threadIdx.x, w = tid >> 6, lane = tid & 63;
    __shared__ unsigned long long pendS[16];
    __shared__ unsigned long long defS[16];
    __shared__ unsigned long long KS[NLV][1024];
    __shared__ unsigned long long kd[NLV][16];
    __shared__ int kpre[NLV][17];
    __shared__ int lcnt[NLV];

    // ---- scan phase (identical fixpoint) ----
    int cnt = ccnt[nl];
    int nw = (cnt + 63) / 64;
    const unsigned long long* base = MT + ((size_t)nl * 16 + w) * 1024;
    unsigned long long Dmask = 0;
    if (w < nw)
        Dmask = base[(size_t)w * 64 + lane] & ~((2ull << lane) - 1ull);
    unsigned long long rows[15];
    #pragma unroll
    for (int cc = 0; cc < 15; ++cc)
        rows[cc] = (cc < w && w < nw) ? base[(size_t)cc * 64 + lane] : 0ull;

    int nb = max(0, min(64, cnt - w * 64));
    unsigned long long pend_w = (nb == 64) ? ~0ull : ((nb > 0) ? ((1ull << nb) - 1ull) : 0ull);
    unsigned long long K_w = 0;
    if (lane == 0) pendS[w] = pend_w;
    __syncthreads();

    for (int round = 0; round < 1024; ++round) {
        unsigned long long any = 0;
        #pragma unroll
        for (int cc = 0; cc < 16; ++cc) any |= pendS[cc];
        if (!any) break;
        unsigned long long acc = ((pendS[w] >> lane) & 1ull) ? Dmask : 0ull;
        #pragma unroll
        for (int cc = 0; cc < 15; ++cc)
            if (cc < w) acc |= ((pendS[cc] >> lane) & 1ull) ? rows[cc] : 0ull;
        unsigned int vlo = (unsigned int)acc, vhi = (unsigned int)(acc >> 32);
        #pragma unroll
        for (int m = 1; m < 64; m <<= 1) {
            vlo |= (unsigned int)__shfl_xor((int)vlo, m, 64);
            vhi |= (unsigned int)__shfl_xor((int)vhi, m, 64);
        }
        unsigned long long sup = ((unsigned long long)vhi << 32) | (unsigned long long)vlo;
        unsigned long long def_w = pend_w & ~sup;
        K_w |= def_w;
        if (lane == 0) defS[w] = def_w;
        __syncthreads();
        unsigned long long acc2 = ((defS[w] >> lane) & 1ull) ? Dmask : 0ull;
        #pragma unroll
        for (int cc = 0; cc < 15; ++cc)
            if (cc < w) acc2 |= ((defS[cc] >> lane) & 1ull) ? rows[cc] : 0ull;
        unsigned int rlo = (unsigned int)acc2, rhi = (unsigned int)(acc2 >> 32);
        #pragma unroll
        for (int m = 1; m < 64; m <<= 1) {
            rlo |= (unsigned int)__shfl_xor((int)rlo, m, 64);
            rhi |= (unsigned int)__shfl_xor((int)rhi, m, 64);
        }
        unsigned long long rem = ((unsigned long long)rhi << 32) | (unsigned long long)rlo;
        pend_w &= ~def_w & ~rem;
        if (lane == 0) pendS[w] = pend_w;
        __syncthreads();
    }
    if (lane == 0)
        __hip_atomic_store(&keepL[nl * 16 + w], K_w, __ATOMIC_RELAXED,
                           __HIP_MEMORY_SCOPE_AGENT);
    __syncthreads();   // vmcnt drained -> keepL stores complete
    if (tid == 0)
        astore(&kdone[nl], MG_KDN + (unsigned)nl, __ATOMIC_RELEASE);

    // ---- handshake: wait for all 5 levels of this image ----
    if (tid < NLV) {
        unsigned int want = MG_KDN + (unsigned)(n * NLV + tid);
        while (aload(&kdone[n * NLV + tid], __ATOMIC_ACQUIRE) != want)
            __builtin_amdgcn_s_sleep(8);
    }
    __syncthreads();

    // ---- rank phase (identical arithmetic; out pre-zeroed by k_mask) ----
    for (int e = tid; e < NLV * 1024; e += 1024)
        ((unsigned long long*)KS)[e] = skey[(size_t)n * NLV * 1024 + e];
    if (tid < NLV * 16)
        ((unsigned long long*)kd)[tid] =
            __hip_atomic_load(&keepL[n * NLV * 16 + tid], __ATOMIC_RELAXED,
                              __HIP_MEMORY_SCOPE_AGENT);
    if (tid < NLV) lcnt[tid] = ccnt[n * NLV + tid];
    __syncthreads();
    if (tid < NLV) {
        int run = 0;
        for (int q = 0; q < 16; ++q) { kpre[tid][q] = run; run += (int)__popcll(kd[tid][q]); }
        kpre[tid][16] = run;
    }
    __syncthreads();
    int i = tid;
    if (i >= lcnt[l]) return;
    int q = i >> 6, b = i & 63;
    if (!((kd[l][q] >> b) & 1ull)) return;
    int rank = kpre[l][q] + (int)__popcll(kd[l][q] & ((1ull << b) - 1ull));
    unsigned int sk = (unsigned int)(KS[l][i] >> 27);
    for (int l2 = 0; l2 < NLV; ++l2) {
        if (l2 == l) continue;
        int c2 = lcnt[l2];
        unsigned long long bound = (l2 < l)
            ? (((unsigned long long)sk + 1ull) << 27)   // sk' <= sk
            : ((unsigned long long)sk << 27);           // sk' <  sk
        int lo = 0, hi = c2;
        while (lo < hi) {
            int mid = (lo + hi) >> 1;
            if (KS[l2][mid] < bound) lo = mid + 1; else hi = mid;
        }
        int mq = lo >> 6, mb = lo & 63;
        rank += kpre[l2][mq] + (mb ? (int)__popcll(kd[l2][mq] & ((1ull << mb) - 1ull)) : 0);
    }
    if (rank < POSTN) {
        ((float4*)out)[n * POSTN + rank] = sboxL[(size_t)(n * NLV + l) * 1024 + i];
        float lg = slogL[(size_t)(n * NLV + l) * 1024 + i];
        out[NIMG * POSTN * 4 + n * POSTN + rank] = 1.0f / (1.0f + expf(-lg));
    }
}

extern "C" void kernel_launch(void* const* d_in, const int* in_sizes, int n_in,
                              void* d_out, int out_size, void* d_ws, size_t ws_size,
                              hipStream_t stream) {
    Ptrs P;
    bool interleaved = (in_sizes[1] == 4 * in_sizes[0]);
    for (int i = 0; i < NLV; ++i) {
        if (interleaved) {
            P.obj[i] = (const float*)d_in[2 * i];
            P.del[i] = (const float*)d_in[2 * i + 1];
        } else {
            P.obj[i] = (const float*)d_in[i];
            P.del[i] = (const float*)d_in[NLV + i];
        }
    }
    P.anch = (const float*)d_in[10];

    char* w = (char*)d_ws;
    size_t off = 0;
    auto alloc = [&](size_t bytes) {
        void* p = w + off;
        off = (off + bytes + 255) & ~(size_t)255;
        return p;
    };
    const size_t NLT = (size_t)NIMG * NLV * 1024;
    unsigned int* hist = (unsigned int*)alloc((size_t)NIMG * NLV * NHB * 2048 * 4);
    int* scnt = (int*)alloc(256);
    int* tcnt = (int*)alloc(256);
    unsigned int* thr = (unsigned int*)alloc((size_t)NIMG * NLV * 2 * 4);
    unsigned int* subflag = (unsigned int*)alloc((size_t)NIMG * NLV * NHB * 4);
    unsigned int* ready = (unsigned int*)alloc(128);
    unsigned int* kdone = (unsigned int*)alloc(128);
    unsigned long long* tiebuf = (unsigned long long*)alloc((size_t)NIMG * NLV * TCAP * 8);
    int* cg      = (int*)alloc((size_t)TSEL * 4);
    float* cl    = (float*)alloc((size_t)TSEL * 4);
    unsigned long long* skey = (unsigned long long*)alloc(NLT * 8);
    float4* sboxL = (float4*)alloc(NLT * 16);
    float* slogL  = (float*)alloc(NLT * 4);
    int* ccnt    = (int*)alloc((size_t)NIMG * NLV * 4);
    unsigned long long* keepL = (unsigned long long*)alloc((size_t)NIMG * NLV * 16 * 8);
    unsigned long long* MT = (unsigned long long*)alloc((size_t)NIMG * NLV * 16 * 1024 * 8);
    (void)ws_size; (void)n_in;

    k_htp<<<NIMG * NLV * PBLK, 256, 0, stream>>>(P, hist, subflag, ready, thr,
                                                 scnt, tcnt, cg, cl, tiebuf, kdone);
    k_tbs<<<dim3(NLV, NIMG), 1024, 0, stream>>>(P, thr, tcnt, tiebuf, cg, cl,
                                                skey, sboxL, slogL, ccnt,
                                                subflag, ready);
    k_mask<<<dim3(256, NLV, NIMG), 256, 0, stream>>>(sboxL, ccnt, MT, (float*)d_out);
    k_scanrank2<<<dim3(NLV, NIMG), 1024, 0, stream>>>(MT, ccnt, skey, sboxL, slogL,
                                                      keepL, kdone, (float*)d_out);
}

// Round 6
// 158.897 us; speedup vs baseline: 2.3478x; 2.3478x over previous
//
#include <hip/hip_runtime.h>
#include <cstdint>
#include <cstddef>

#define NLV 5
#define NIMG 4
#define NSEL 4507          // 1000+1000+1000+1000+507 selected per image
#define TSEL (NIMG * NSEL)
#define POSTN 1000
#define TCAP 8192          // boundary-bin candidate cap
#define TTCAP 2048         // sub-boundary (tie-of-tie) cap
#define NHB 16             // sub-histograms per (image,level)
#define PBLK 64            // pick blocks per (image,level)
#define PCH 1875           // max chunk for pick (120000/64)

__device__ const int d_W[NLV]    = {200, 100, 50, 25, 13};
__device__ const int d_NL[NLV]   = {120000, 30000, 7500, 1875, 507};
__device__ const int d_KOFF[6]   = {0, 120000, 150000, 157500, 159375, 159882};
__device__ const int d_LOFF[6]   = {0, 1000, 2000, 3000, 4000, 4507};
__device__ const int d_KL[NLV]   = {1000, 1000, 1000, 1000, 507};

struct Ptrs {
    const float* obj[NLV];
    const float* del[NLV];
    const float* anch;
};

// order-preserving map: dk ascending <=> float descending
__device__ inline unsigned int dkey_of(float f) {
    unsigned int u = __float_as_uint(f);
    unsigned int mk = (u & 0x80000000u) ? ~u : (u | 0x80000000u);
    return ~mk;
}
__device__ inline float logit_from_dkey(unsigned int dk) {
    unsigned int mk = ~dk;
    unsigned int u = (mk & 0x80000000u) ? (mk & 0x7fffffffu) : ~mk;
    return __uint_as_float(u);
}

// ---------------- stage 1: LDS-private histograms, plain stores -------------
// 256 threads/block, 16 blocks per (image,level): measured-best config
// (1024-thr single-block variant regressed: hot-bin LDS atomic serialization;
// rounds 4/5: grid.sync / spin+agent-atomics both FAR worse than a dispatch
// boundary on 8-XCD MI355X — never sync device-wide inside a kernel).
// Also zero-inits scnt/tcnt (consumed 2 dispatches later by pick).
__global__ __launch_bounds__(256) void k_hist(Ptrs P, unsigned int* hist,
                                              int* scnt, int* tcnt) {
    int l = blockIdx.y, n = blockIdx.z;
    int nlid = n * NLV + l;
    if (blockIdx.x == 0 && threadIdx.x == 0) { scnt[nlid] = 0; tcnt[nlid] = 0; }
    int nl_sz = d_NL[l];
    if (d_KL[l] >= nl_sz) return;            // level 4: all selected
    __shared__ unsigned int h[2048];
    for (int i = threadIdx.x; i < 2048; i += 256) h[i] = 0;
    __syncthreads();
    const float* ob = P.obj[l] + (size_t)n * nl_sz;
    int chunk = (nl_sz + NHB - 1) / NHB;
    int beg = blockIdx.x * chunk;
    int end = min(beg + chunk, nl_sz);
    for (int t = beg + (int)threadIdx.x; t < end; t += 256)
        atomicAdd(&h[dkey_of(ob[t]) >> 21], 1u);   // LDS atomic
    __syncthreads();
    unsigned int* out = hist + ((size_t)nlid * NHB + blockIdx.x) * 2048;
    for (int i = threadIdx.x; i < 2048; i += 256) out[i] = h[i];
}

// ---------------- stage 2: thresh (redundant per-block) + pick fused --------
// Each of the 1280 blocks re-reduces its (n,l)'s 16 sub-hists (L2-resident,
// ~2-3us, fully parallel) and derives the threshold locally — deterministic
// arithmetic => all 64 blocks of an (n,l) agree bit-exactly. Saves the
// k_thresh dispatch with ZERO cross-block communication (round-5 lesson).
// Thresh math = round-5 phase-T (proven, absmax 0). Block x==0 publishes
// thr[] for k_tbs across the dispatch boundary (plain store).
__global__ __launch_bounds__(256) void k_pickT(Ptrs P, const unsigned int* hist,
                                               unsigned int* thr,
                                               int* scnt, int* tcnt,
                                               int* cg, float* cl,
                                               unsigned long long* tiebuf) {
    int l = blockIdx.y, n = blockIdx.z;
    int nl_sz = d_NL[l], kl = d_KL[l];
    int nlid = n * NLV + l;
    const float* ob = P.obj[l] + (size_t)n * nl_sz;
    int cbase = n * NSEL + d_LOFF[l];
    int koff = d_KOFF[l];
    int Wl = d_W[l], HW = Wl * Wl;
    int chunk = (nl_sz + PBLK - 1) / PBLK;
    int beg = blockIdx.x * chunk;
    int end = min(beg + chunk, nl_sz);
    int tid = threadIdx.x;

    if (kl >= nl_sz) {                       // level 4: deterministic slots
        for (int t = beg + tid; t < end; t += 256) {
            int a = t / HW, rem = t - a * HW;
            int p = rem * 3 + a;
            cg[cbase + p] = koff + p;
            cl[cbase + p] = ob[t];
        }
        return;
    }

    // ---- local threshold: reduce 16 sub-hists, find boundary bin ----
    __shared__ unsigned int pw4[4];
    __shared__ unsigned int s_b0, s_cntlt;
    {
        unsigned int bins[8];
        #pragma unroll
        for (int i = 0; i < 8; ++i) bins[i] = 0;
        const unsigned int* hb = hist + (size_t)nlid * NHB * 2048;
        for (int sh = 0; sh < NHB; ++sh) {
            #pragma unroll
            for (int i = 0; i < 8; ++i)
                bins[i] += hb[sh * 2048 + tid * 8 + i];   // thread owns bins [8t,8t+8)
        }
        unsigned int s = 0;
        #pragma unroll
        for (int i = 0; i < 8; ++i) s += bins[i];
        int w4 = tid >> 6, lane = tid & 63;
        unsigned int ps = s;
        #pragma unroll
        for (int d = 1; d < 64; d <<= 1) {
            unsigned int t2 = (unsigned int)__shfl_up((int)ps, d, 64);
            if (lane >= d) ps += t2;
        }
        if (lane == 63) pw4[w4] = ps;
        __syncthreads();
        unsigned int base = 0;
        #pragma unroll
        for (int ww = 0; ww < 4; ++ww) if (ww < w4) base += pw4[ww];
        unsigned int exc = base + ps - s;    // exclusive prefix before bin 8t
        unsigned int target = (unsigned int)kl;
        unsigned int cum = exc;
        #pragma unroll
        for (int i = 0; i < 8; ++i) {        // exactly one (t,i) hits
            if (cum < target && target <= cum + bins[i]) {
                s_b0 = (unsigned int)(tid * 8 + i);
                s_cntlt = cum;
            }
            cum += bins[i];
        }
        __syncthreads();
        if (blockIdx.x == 0 && tid == 0) {   // publish for k_tbs
            thr[nlid * 2] = s_b0;
            thr[nlid * 2 + 1] = s_cntlt;
        }
    }

    // ---- pick phase (round-3 proven, b0 from LDS) ----
    __shared__ int sp[PCH];
    __shared__ float sl[PCH];
    __shared__ unsigned long long tb[PCH];
    __shared__ int nsel, ntie, sbase, tbase;
    if (tid == 0) { nsel = 0; ntie = 0; }
    __syncthreads();

    unsigned int b0 = s_b0;
    for (int t = beg + tid; t < end; t += 256) {
        float lg = ob[t];
        unsigned int dk = dkey_of(lg);
        unsigned int bin = dk >> 21;
        if (bin < b0) {
            int pos = atomicAdd(&nsel, 1);   // LDS atomic
            int a = t / HW, rem = t - a * HW;
            sp[pos] = rem * 3 + a;
            sl[pos] = lg;
        } else if (bin == b0) {
            int pos = atomicAdd(&ntie, 1);   // LDS atomic
            int a = t / HW, rem = t - a * HW;
            tb[pos] = ((unsigned long long)dk << 17) |
                      (unsigned long long)(unsigned int)(rem * 3 + a);
        }
    }
    __syncthreads();
    if (tid == 0) {
        sbase = atomicAdd(&scnt[nlid], nsel);  // 1 global atomic / block
        tbase = atomicAdd(&tcnt[nlid], ntie);
    }
    __syncthreads();
    int ns = nsel, nt = ntie, sb = sbase, tbs = tbase;
    for (int i = tid; i < ns; i += 256) {
        cg[cbase + sb + i] = koff + sp[i];
        cl[cbase + sb + i] = sl[i];
    }
    for (int i = tid; i < nt; i += 256) {
        int slot = tbs + i;
        if (slot < TCAP) tiebuf[(size_t)nlid * TCAP + slot] = tb[i];
    }
}

// ---------------- stage 3: tie + build + sort fused (per (image,level)) -----
__global__ __launch_bounds__(1024) void k_tbs(Ptrs P, const unsigned int* thr,
                                              const int* tcnt,
                                              const unsigned long long* tiebuf,
                                              int* cg, float* cl,
                                              unsigned long long* skey,
                                              float4* sboxL, float* slogL,
                                              int* ccnt) {
#pragma clang fp contract(off)
    __shared__ union {
        struct { unsigned long long kk[TCAP];         // 64KB
                 unsigned long long tt[TTCAP];        // 16KB
                 unsigned int h2[2048]; } tie;        //  8KB  -> 88KB
        struct { unsigned long long s[1024];          //  8KB
                 float4 bx[1024];                     // 16KB
                 float lg[1024]; } srt;               //  4KB  -> 28KB
    } U;
    __shared__ unsigned int wpre[16];
    __shared__ unsigned int s_b1, s_before;
    __shared__ int ctr, ttc;

    int l = blockIdx.x, n = blockIdx.y;
    int nl = n * NLV + l;
    int tid = threadIdx.x, w = tid >> 6, lane = tid & 63;
    int kl = d_KL[l], nl_sz = d_NL[l];
    int cbase = n * NSEL + d_LOFF[l];
    int koff = d_KOFF[l];

    // ---- phase A: boundary-bin candidates, radix-refined ----
    if (kl < nl_sz) {
        int c = min(tcnt[nl], TCAP);
        unsigned int cnt_lt = thr[nl * 2 + 1];
        int need = kl - (int)cnt_lt;
        if (tid == 0) { ctr = 0; ttc = 0; }
        U.tie.h2[tid] = 0; U.tie.h2[tid + 1024] = 0;
        for (int i = tid; i < c; i += 1024) U.tie.kk[i] = tiebuf[(size_t)nl * TCAP + i];
        __syncthreads();
        for (int i = tid; i < c; i += 1024)
            atomicAdd(&U.tie.h2[(unsigned int)((U.tie.kk[i] >> 27) & 0x7ffull)], 1u);
        __syncthreads();
        unsigned int v0 = U.tie.h2[2 * tid], v1 = U.tie.h2[2 * tid + 1];
        unsigned int s = v0 + v1, ps = s;
        #pragma unroll
        for (int d = 1; d < 64; d <<= 1) {
            unsigned int t2 = (unsigned int)__shfl_up((int)ps, d, 64);
            if (lane >= d) ps += t2;
        }
        if (lane == 63) wpre[w] = ps;
        __syncthreads();
        unsigned int base = 0;
        #pragma unroll
        for (int ww = 0; ww < 16; ++ww) if (ww < w) base += wpre[ww];
        unsigned int incl = base + ps;
        unsigned int target = (unsigned int)need;
        unsigned int exc0 = incl - s, inc0 = incl - v1;
        unsigned int exc1 = inc0,    inc1 = incl;
        if (exc0 < target && target <= inc0) { s_b1 = 2 * tid;     s_before = exc0; }
        if (exc1 < target && target <= inc1) { s_b1 = 2 * tid + 1; s_before = exc1; }
        __syncthreads();
        unsigned int b1 = s_b1;
        int before = (int)s_before;
        for (int i = tid; i < c; i += 1024) {
            unsigned long long ki = U.tie.kk[i];
            unsigned int sb = (unsigned int)((ki >> 27) & 0x7ffull);
            if (sb < b1) {                   // sure winner, arbitrary slot
                int slot = atomicAdd(&ctr, 1);
                int p = (int)(ki & 0x1ffffull);
                cg[cbase + (int)cnt_lt + slot] = koff + p;
                cl[cbase + (int)cnt_lt + slot] = logit_from_dkey((unsigned int)(ki >> 17));
            } else if (sb == b1) {
                int j = atomicAdd(&ttc, 1);
                if (j < TTCAP) U.tie.tt[j] = ki;
            }
        }
        __syncthreads();
        int c2 = min(ttc, TTCAP);
        int need2 = need - before;
        for (int i = tid; i < c2; i += 1024) {
            unsigned long long ki = U.tie.tt[i];
            int rank = 0;
            for (int j = 0; j < c2; ++j) rank += (U.tie.tt[j] < ki) ? 1 : 0;
            if (rank < need2) {              // ranks unique (p unique)
                int p = (int)(ki & 0x1ffffull);
                cg[cbase + (int)cnt_lt + before + rank] = koff + p;
                cl[cbase + (int)cnt_lt + before + rank] = logit_from_dkey((unsigned int)(ki >> 17));
            }
        }
    }
    __syncthreads();   // phase A LDS dead; cg/cl visible block-wide

    // ---- phase B: decode, clip, validity, into LDS ----
    {
        int j = tid;
        unsigned long long key;
        float4 box;
        float lgv;
        if (j >= kl) {                       // padding slot
            key = ((unsigned long long)0xFFFFFFFFu << 27) | (unsigned long long)j;
            box = make_float4(0.f, 0.f, 0.f, 0.f);
            lgv = 0.f;
        } else {
            int sidx = cbase + j;
            int gidx = cg[sidx];
            float lg = cl[sidx];
            int p = gidx - koff;
            int Wl = d_W[l];
            int HW = Wl * Wl;
            int a = p % 3, hw = p / 3;
            int hq = hw / Wl, wq = hw - hq * Wl;
            const float* dl = P.del[l];
            size_t dbase = (size_t)(n * 12 + a * 4) * HW + (size_t)hq * Wl + wq;
            float dx = dl[dbase], dy = dl[dbase + HW];
            float dw = dl[dbase + 2 * (size_t)HW], dh = dl[dbase + 3 * (size_t)HW];
            const float* an = P.anch + 4 * (size_t)gidx;
            float ax1 = an[0], ay1 = an[1], ax2 = an[2], ay2 = an[3];
            float wa = ax2 - ax1, ha = ay2 - ay1;
            float cxa = ax1 + 0.5f * wa, cya = ay1 + 0.5f * ha;
            const float CLIPC = (float)4.135166556742356;
            dw = fminf(dw, CLIPC); dh = fminf(dh, CLIPC);
            float cx = dx * wa + cxa;
            float cy = dy * ha + cya;
            float ww2 = expf(dw) * wa;
            float hh2 = expf(dh) * ha;
            float x1 = cx - 0.5f * ww2, y1 = cy - 0.5f * hh2;
            float x2 = cx + 0.5f * ww2, y2 = cy + 0.5f * hh2;
            x1 = fminf(fmaxf(x1, 0.0f), 800.0f);
            y1 = fminf(fmaxf(y1, 0.0f), 800.0f);
            x2 = fminf(fmaxf(x2, 0.0f), 800.0f);
            y2 = fminf(fmaxf(y2, 0.0f), 800.0f);
            bool valid = (x2 - x1 >= 1e-3f) && (y2 - y1 >= 1e-3f);
            box = make_float4(x1, y1, x2, y2);
            lgv = lg;
            unsigned int sk = valid ? dkey_of(lg) : 0xffffffffu;
            key = ((unsigned long long)sk << 27) |
                  ((unsigned long long)(unsigned int)p << 10) | (unsigned long long)j;
        }
        U.srt.s[j] = key;
        U.srt.bx[j] = box;
        U.srt.lg[j] = lgv;
    }
    __syncthreads();

    // ---- phase C: bitonic sort of 1024 keys (512 active) ----
    for (int k = 2; k <= 1024; k <<= 1) {
        for (int j2 = k >> 1; j2 > 0; j2 >>= 1) {
            if (tid < 512) {
                int i = ((tid & ~(j2 - 1)) << 1) | (tid & (j2 - 1));
                int ix = i | j2;
                bool up = ((i & k) == 0);
                unsigned long long A = U.srt.s[i], B = U.srt.s[ix];
                if ((A > B) == up) { U.srt.s[i] = B; U.srt.s[ix] = A; }
            }
            __syncthreads();
        }
    }
    {
        int e = tid;
        unsigned long long key = U.srt.s[e];
        int j = (int)(key & 0x3ffull);
        skey[(size_t)nl * 1024 + e] = key;
        sboxL[(size_t)nl * 1024 + e] = U.srt.bx[j];
        slogL[(size_t)nl * 1024 + e] = U.srt.lg[j];
        bool v = (key >> 27) != 0xFFFFFFFFull;
        bool vn = (e < 1023) ? ((U.srt.s[e + 1] >> 27) != 0xFFFFFFFFull) : false;
        if (e == 0 && !v) ccnt[nl] = 0;
        if (v && (e == 1023 || !vn)) ccnt[nl] = e + 1;
    }
}

// --------------- pairwise suppression mask, whole-chip parallel -------------
// MT TRANSPOSED: MT[(nl*16 + colword)*1024 + row]. Upper triangle only.
__global__ __launch_bounds__(256) void k_mask(const float4* sboxL, const int* ccnt,
                                              unsigned long long* MT) {
#pragma clang fp contract(off)
    int n = blockIdx.z, l = blockIdx.y;
    int ci = blockIdx.x >> 4, cj = blockIdx.x & 15;
    int nl = n * NLV + l;
    int cnt = ccnt[nl];
    int nw = (cnt + 63) / 64;
    if (cj < ci || cj >= nw) return;
    __shared__ float4 bi[64], bj[64];
    int tid = threadIdx.x;
    float off = (float)l * 801.0f;
    if (tid < 64) {
        float4 b = sboxL[nl * 1024 + cj * 64 + tid];
        bj[tid] = make_float4(b.x + off, b.y + off, b.z + off, b.w + off);
    } else if (tid < 128) {
        float4 b = sboxL[nl * 1024 + ci * 64 + (tid - 64)];
        bi[tid - 64] = make_float4(b.x + off, b.y + off, b.z + off, b.w + off);
    }
    __syncthreads();
    int w = tid >> 6, lane = tid & 63;
    float4 B = bj[lane];
    float a2 = (B.z - B.x) * (B.w - B.y);
    unsigned long long* outp = MT + ((size_t)nl * 16 + cj) * 1024 + ci * 64;
    #pragma unroll
    for (int t = 0; t < 16; ++t) {
        int i = w * 16 + t;
        float4 A = bi[i];
        float a1 = (A.z - A.x) * (A.w - A.y);
        float ltx = fmaxf(A.x, B.x), lty = fmaxf(A.y, B.y);
        float rbx = fminf(A.z, B.z), rby = fminf(A.w, B.w);
        float wx = fmaxf(rbx - ltx, 0.f), wy = fmaxf(rby - lty, 0.f);
        float inter = wx * wy;
        float iou = inter / ((a1 + a2) - inter);   // NaN (0/0) -> false, like jnp
        unsigned long long word = __ballot(iou > 0.7f);
        if (lane == 0) outp[i] = word;
    }
}

// --------------- batched greedy NMS scan: fixpoint rounds, 20-way parallel --
// Also zeroes this block's 1/5 slice of the output image (strictly before
// k_rank in stream order).
__global__ __launch_bounds__(1024) void k_scan(const unsigned long long* MT,
                                               const int* ccnt,
                                               unsigned long long* keepL,
                                               float* out) {
    int l = blockIdx.x, n = blockIdx.y;
    int nl = n * NLV + l;
    int tid = threadIdx.x, w = tid >> 6, lane = tid & 63;
    __shared__ unsigned long long pendS[16];
    __shared__ unsigned long long defS[16];
    {
        int seg = POSTN / NLV;
        for (int i = tid; i < seg; i += 1024) {
            int idx = n * POSTN + l * seg + i;
            ((float4*)out)[idx] = make_float4(0.f, 0.f, 0.f, 0.f);
            out[NIMG * POSTN * 4 + idx] = 0.f;
        }
    }
    int cnt = ccnt[nl];
    int nw = (cnt + 63) / 64;

    const unsigned long long* base = MT + ((size_t)nl * 16 + w) * 1024;
    unsigned long long Dmask = 0;
    if (w < nw)
        Dmask = base[(size_t)w * 64 + lane] & ~((2ull << lane) - 1ull);
    unsigned long long rows[15];
    #pragma unroll
    for (int cc = 0; cc < 15; ++cc)
        rows[cc] = (cc < w && w < nw) ? base[(size_t)cc * 64 + lane] : 0ull;

    int nb = max(0, min(64, cnt - w * 64));
    unsigned long long pend_w = (nb == 64) ? ~0ull : ((nb > 0) ? ((1ull << nb) - 1ull) : 0ull);
    unsigned long long K_w = 0;
    if (lane == 0) pendS[w] = pend_w;
    __syncthreads();

    for (int round = 0; round < 1024; ++round) {
        unsigned long long any = 0;
        #pragma unroll
        for (int cc = 0; cc < 16; ++cc) any |= pendS[cc];
        if (!any) break;
        unsigned long long acc = ((pendS[w] >> lane) & 1ull) ? Dmask : 0ull;
        #pragma unroll
        for (int cc = 0; cc < 15; ++cc)
            if (cc < w) acc |= ((pendS[cc] >> lane) & 1ull) ? rows[cc] : 0ull;
        unsigned int vlo = (unsigned int)acc, vhi = (unsigned int)(acc >> 32);
        #pragma unroll
        for (int m = 1; m < 64; m <<= 1) {
            vlo |= (unsigned int)__shfl_xor((int)vlo, m, 64);
            vhi |= (unsigned int)__shfl_xor((int)vhi, m, 64);
        }
        unsigned long long sup = ((unsigned long long)vhi << 32) | (unsigned long long)vlo;
        unsigned long long def_w = pend_w & ~sup;
        K_w |= def_w;
        if (lane == 0) defS[w] = def_w;
        __syncthreads();
        unsigned long long acc2 = ((defS[w] >> lane) & 1ull) ? Dmask : 0ull;
        #pragma unroll
        for (int cc = 0; cc < 15; ++cc)
            if (cc < w) acc2 |= ((defS[cc] >> lane) & 1ull) ? rows[cc] : 0ull;
        unsigned int rlo = (unsigned int)acc2, rhi = (unsigned int)(acc2 >> 32);
        #pragma unroll
        for (int m = 1; m < 64; m <<= 1) {
            rlo |= (unsigned int)__shfl_xor((int)rlo, m, 64);
            rhi |= (unsigned int)__shfl_xor((int)rhi, m, 64);
        }
        unsigned long long rem = ((unsigned long long)rhi << 32) | (unsigned long long)rlo;
        pend_w &= ~def_w & ~rem;
        if (lane == 0) pendS[w] = pend_w;
        __syncthreads();
    }
    if (lane == 0) keepL[nl * 16 + w] = K_w;
}

// --------------- rank-merge, 20-way parallel: one block per (image,level) ---
// Score ties across levels: reference tiebreak is level asc — bounds compare
// sk only: l2<l counts sk'<=sk, l2>l counts sk'<sk.
__global__ __launch_bounds__(1024) void k_rank(const unsigned long long* skey,
                                               const unsigned long long* keepL,
                                               const int* ccnt,
                                               const float4* sboxL, const float* slogL,
                                               float* out) {
    int l = blockIdx.x, n = blockIdx.y;
    int tid = threadIdx.x;
    __shared__ unsigned long long KS[NLV][1024];
    __shared__ unsigned long long kd[NLV][16];
    __shared__ int kpre[NLV][17];
    __shared__ int lcnt[NLV];
    for (int e = tid; e < NLV * 1024; e += 1024)
        ((unsigned long long*)KS)[e] = skey[(size_t)n * NLV * 1024 + e];
    if (tid < NLV * 16) ((unsigned long long*)kd)[tid] = keepL[n * NLV * 16 + tid];
    if (tid < NLV) lcnt[tid] = ccnt[n * NLV + tid];
    __syncthreads();
    if (tid < NLV) {
        int run = 0;
        for (int q = 0; q < 16; ++q) { kpre[tid][q] = run; run += (int)__popcll(kd[tid][q]); }
        kpre[tid][16] = run;
    }
    __syncthreads();
    int i = tid;
    if (i >= lcnt[l]) return;
    int q = i >> 6, b = i & 63;
    if (!((kd[l][q] >> b) & 1ull)) return;
    int rank = kpre[l][q] + (int)__popcll(kd[l][q] & ((1ull << b) - 1ull));
    unsigned int sk = (unsigned int)(KS[l][i] >> 27);
    for (int l2 = 0; l2 < NLV; ++l2) {
        if (l2 == l) continue;
        int c2 = lcnt[l2];
        unsigned long long bound = (l2 < l)
            ? (((unsigned long long)sk + 1ull) << 27)   // sk' <= sk
            : ((unsigned long long)sk << 27);           // sk' <  sk
        int lo = 0, hi = c2;
        while (lo < hi) {
            int mid = (lo + hi) >> 1;
            if (KS[l2][mid] < bound) lo = mid + 1; else hi = mid;
        }
        int mq = lo >> 6, mb = lo & 63;
        rank += kpre[l2][mq] + (mb ? (int)__popcll(kd[l2][mq] & ((1ull << mb) - 1ull)) : 0);
    }
    if (rank < POSTN) {
        ((float4*)out)[n * POSTN + rank] = sboxL[(size_t)(n * NLV + l) * 1024 + i];
        float lg = slogL[(size_t)(n * NLV + l) * 1024 + i];
        out[NIMG * POSTN * 4 + n * POSTN + rank] = 1.0f / (1.0f + expf(-lg));
    }
}

extern "C" void kernel_launch(void* const* d_in, const int* in_sizes, int n_in,
                              void* d_out, int out_size, void* d_ws, size_t ws_size,
                              hipStream_t stream) {
    Ptrs P;
    bool interleaved = (in_sizes[1] == 4 * in_sizes[0]);
    for (int i = 0; i < NLV; ++i) {
        if (interleaved) {
            P.obj[i] = (const float*)d_in[2 * i];
            P.del[i] = (const float*)d_in[2 * i + 1];
        } else {
            P.obj[i] = (const float*)d_in[i];
            P.del[i] = (const float*)d_in[NLV + i];
        }
    }
    P.anch = (const float*)d_in[10];

    char* w = (char*)d_ws;
    size_t off = 0;
    auto alloc = [&](size_t bytes) {
        void* p = w + off;
        off = (off + bytes + 255) & ~(size_t)255;
        return p;
    };
    const size_t NLT = (size_t)NIMG * NLV * 1024;
    unsigned int* hist = (unsigned int*)alloc((size_t)NIMG * NLV * NHB * 2048 * 4);
    int* scnt = (int*)alloc(256);
    int* tcnt = (int*)alloc(256);
    unsigned int* thr = (unsigned int*)alloc((size_t)NIMG * NLV * 2 * 4);
    unsigned long long* tiebuf = (unsigned long long*)alloc((size_t)NIMG * NLV * TCAP * 8);
    int* cg      = (int*)alloc((size_t)TSEL * 4);
    float* cl    = (float*)alloc((size_t)TSEL * 4);
    unsigned long long* skey = (unsigned long long*)alloc(NLT * 8);
    float4* sboxL = (float4*)alloc(NLT * 16);
    float* slogL  = (float*)alloc(NLT * 4);
    int* ccnt    = (int*)alloc((size_t)NIMG * NLV * 4);
    unsigned long long* keepL = (unsigned long long*)alloc((size_t)NIMG * NLV * 16 * 8);
    unsigned long long* MT = (unsigned long long*)alloc((size_t)NIMG * NLV * 16 * 1024 * 8);
    (void)ws_size; (void)n_in;

    k_hist<<<dim3(NHB, NLV, NIMG), 256, 0, stream>>>(P, hist, scnt, tcnt);
    k_pickT<<<dim3(PBLK, NLV, NIMG), 256, 0, stream>>>(P, hist, thr, scnt, tcnt,
                                                       cg, cl, tiebuf);
    k_tbs<<<dim3(NLV, NIMG), 1024, 0, stream>>>(P, thr, tcnt, tiebuf, cg, cl,
                                                skey, sboxL, slogL, ccnt);
    k_mask<<<dim3(256, NLV, NIMG), 256, 0, stream>>>(sboxL, ccnt, MT);
    k_scan<<<dim3(NLV, NIMG), 1024, 0, stream>>>(MT, ccnt, keepL, (float*)d_out);
    k_rank<<<dim3(NLV, NIMG), 1024, 0, stream>>>(skey, keepL, ccnt, sboxL, slogL, (float*)d_out);
}